// Round 11
// baseline (238.137 us; speedup 1.0000x reference)
//
#include <hip/hip_runtime.h>
#include <hip/hip_bf16.h>

// Problem constants (fixed by setup_inputs)
#define NB   8      // batch
#define DK   256    // dk (4 mixtures x 64)
#define LL   2048   // Lq == Lk
#define DV   256    // dv
#define NMIX 4
#define EPA  136    // qk_attn E pitch (shorts)

typedef __attribute__((ext_vector_type(8))) short bf16x8;
typedef __attribute__((ext_vector_type(4))) short bf16x4;
typedef __attribute__((ext_vector_type(4))) float f32x4;

__device__ __forceinline__ unsigned short f2bf(float x) {
    unsigned int u = __float_as_uint(x);
    return (unsigned short)((u + 0x7FFFu + ((u >> 16) & 1u)) >> 16);  // RNE
}
__device__ __forceinline__ float bf2f(unsigned short u) {
    return __uint_as_float(((unsigned int)u) << 16);
}
__device__ __forceinline__ void nt_store4(float* p, f32x4 v) {
    __builtin_nontemporal_store(v, reinterpret_cast<f32x4*>(p));
}
// async global->LDS: per-lane global src; LDS dest = uniform base + lane*16B
__device__ __forceinline__ void gl16(const unsigned short* g, unsigned short* l) {
    __builtin_amdgcn_global_load_lds(
        (const __attribute__((address_space(1))) unsigned int*)(const void*)g,
        (__attribute__((address_space(3))) unsigned int*)(void*)l, 16, 0, 0);
}
// packed f32x2 -> 2x bf16 (RNE); exact for already-bf16-rounded inputs
__device__ __forceinline__ unsigned int cvtpk_bf16(float lo, float hi) {
    unsigned int r;
    asm("v_cvt_pk_bf16_f32 %0, %1, %2" : "=v"(r) : "v"(lo), "v"(hi));
    return r;
}

// ---------------------------------------------------------------------------
// Pack K and V into exact MFMA B-operand fragment order (1KB per wave-frag).
// Kp[((b*128+kt16)*8+cc)*512 + lane*8+i] = bf16(K[b][cc*32+lg*8+i][kt16*16+lc])
// Vp[((b*64+kt32)*16+vj)*512 + lane*8+i] = bf16(V[b][vj*16+lc][kt32*32+lg*8+i])
__global__ void pack_kv(const float* __restrict__ key,
                        const float* __restrict__ value,
                        unsigned short* __restrict__ Kp,
                        unsigned short* __restrict__ Vp) {
    const int gid0 = blockIdx.x * 256 + threadIdx.x;
    if (blockIdx.x < 2048) {
        const int gid = gid0;                 // 0 .. 524287
        const int lane = gid & 63;
        const int cc   = (gid >> 6) & 7;      // 32-ch chunk
        const int kt   = (gid >> 9) & 127;    // 16-k tile
        const int b    = gid >> 16;
        const int lg = lane >> 4, lc = lane & 15;
        const float* src = key + ((size_t)b * DK + cc * 32 + lg * 8) * LL + kt * 16 + lc;
        bf16x8 o;
        #pragma unroll
        for (int i = 0; i < 8; ++i) o[i] = (short)f2bf(src[(size_t)i * LL]);
        *reinterpret_cast<bf16x8*>(Kp + (size_t)gid * 8) = o;
    } else {
        const int gid = gid0 - 2048 * 256;    // 0 .. 524287
        const int lane = gid & 63;
        const int vj   = (gid >> 6) & 15;
        const int kt   = (gid >> 10) & 63;    // 32-k tile
        const int b    = gid >> 16;
        const int lg = lane >> 4, lc = lane & 15;
        const float* src = value + ((size_t)b * DV + vj * 16 + lc) * LL + kt * 32 + lg * 8;
        float4 v0 = *reinterpret_cast<const float4*>(src);
        float4 v1 = *reinterpret_cast<const float4*>(src + 4);
        bf16x8 o;
        o[0] = (short)f2bf(v0.x); o[1] = (short)f2bf(v0.y);
        o[2] = (short)f2bf(v0.z); o[3] = (short)f2bf(v0.w);
        o[4] = (short)f2bf(v1.x); o[5] = (short)f2bf(v1.y);
        o[6] = (short)f2bf(v1.z); o[7] = (short)f2bf(v1.w);
        *reinterpret_cast<bf16x8*>(Vp + (size_t)gid * 8) = o;
    }
}

// avg_query: one block per (b*DK + d) row, mean over LL
__global__ void avg_k(const float* __restrict__ q, float* __restrict__ avg) {
    const int row = blockIdx.x;
    const float* p = q + (size_t)row * LL;
    float s = 0.f;
    for (int i = threadIdx.x; i < LL; i += 256) s += p[i];
    #pragma unroll
    for (int off = 32; off >= 1; off >>= 1) s += __shfl_down(s, off);
    __shared__ float ps[4];
    if ((threadIdx.x & 63) == 0) ps[threadIdx.x >> 6] = s;
    __syncthreads();
    if (threadIdx.x == 0)
        avg[row] = (ps[0] + ps[1] + ps[2] + ps[3]) * (1.0f / LL);
}

// pi = softmax_m( w[m,:] . avg[b,:] ) ; one wave per b
__global__ void pi_k(const float* __restrict__ wgt, const float* __restrict__ avg,
                     float* __restrict__ piOut) {
    const int b = blockIdx.x;
    const int l = threadIdx.x;   // 0..63
    float part[NMIX] = {0.f, 0.f, 0.f, 0.f};
    for (int d = l; d < DK; d += 64) {
        float a = avg[b * DK + d];
        #pragma unroll
        for (int m = 0; m < NMIX; ++m) part[m] += wgt[m * DK + d] * a;
    }
    #pragma unroll
    for (int off = 1; off < 64; off <<= 1) {
        #pragma unroll
        for (int m = 0; m < NMIX; ++m) part[m] += __shfl_xor(part[m], off);
    }
    float mx = fmaxf(fmaxf(part[0], part[1]), fmaxf(part[2], part[3]));
    float e0 = __expf(part[0] - mx), e1 = __expf(part[1] - mx);
    float e2 = __expf(part[2] - mx), e3 = __expf(part[3] - mx);
    float z = e0 + e1 + e2 + e3;
    float mine = (l == 0) ? e0 : (l == 1) ? e1 : (l == 2) ? e2 : e3;
    if (l < NMIX) piOut[b * NMIX + l] = mine / z;
}

// ---------------------------------------------------------------------------
// Q A-fragment hoist from raw f32 query: A[row=q=lc][ch=lg*8+i]; qf[qt][m][c].
__device__ __forceinline__ void hoist_q2(const float* __restrict__ query,
                                         int b, int qrow0, int lg, int lc,
                                         bf16x8 qf[2][4][2]) {
    #pragma unroll
    for (int qt = 0; qt < 2; ++qt)
        #pragma unroll
        for (int m = 0; m < 4; ++m)
            #pragma unroll
            for (int c = 0; c < 2; ++c) {
                const float* src = query + ((size_t)b * DK + m * 64 + c * 32 + lg * 8) * LL
                                   + qrow0 + qt * 16 + lc;
                bf16x8 f;
                #pragma unroll
                for (int i = 0; i < 8; ++i) f[i] = (short)f2bf(src[(size_t)i * LL]);
                qf[qt][m][c] = f;
            }
}

// ---------------------------------------------------------------------------
// Z pre-pass (unchanged, known-good):
// Zh[kh][b][q][m] = sum_{k in half} exp2(S*ES)
__launch_bounds__(256, 4)
__global__ void zsum_k(const float* __restrict__ query,
                       const unsigned short* __restrict__ Kp,
                       float* __restrict__ Zh) {
    const int bid = blockIdx.x;
    const int b    = bid & 7;             // XCD affinity
    const int qt64 = (bid >> 3) & 63;
    const int kh   = bid >> 9;
    const int qb   = qt64 * 32;
    const int tid  = threadIdx.x;
    const int w = tid >> 6, lane = tid & 63, lg = lane >> 4, lc = lane & 15;

    bf16x8 qf[2][4][2];
    hoist_q2(query, b, qb, lg, lc, qf);

    const unsigned short* kpB = Kp + (size_t)b * 128 * 8 * 512;
    const float ES = 0.09016844005555896f;   // log2(e)/16

    float zs[2][4][4];
    #pragma unroll
    for (int qt = 0; qt < 2; ++qt)
        #pragma unroll
        for (int m = 0; m < 4; ++m)
            #pragma unroll
            for (int r = 0; r < 4; ++r) zs[qt][m][r] = 0.f;

    for (int t = 0; t < 16; ++t) {
        const int ktile = kh * 64 + w * 16 + t;
        const unsigned short* kp = kpB + (size_t)ktile * 8 * 512 + lane * 8;
        #pragma unroll
        for (int m = 0; m < 4; ++m) {
            bf16x8 k0 = *reinterpret_cast<const bf16x8*>(kp + (m * 2 + 0) * 512);
            bf16x8 k1 = *reinterpret_cast<const bf16x8*>(kp + (m * 2 + 1) * 512);
            #pragma unroll
            for (int qt = 0; qt < 2; ++qt) {
                f32x4 s = {0.f, 0.f, 0.f, 0.f};
                s = __builtin_amdgcn_mfma_f32_16x16x32_bf16(qf[qt][m][0], k0, s, 0, 0, 0);
                s = __builtin_amdgcn_mfma_f32_16x16x32_bf16(qf[qt][m][1], k1, s, 0, 0, 0);
                #pragma unroll
                for (int r = 0; r < 4; ++r)
                    zs[qt][m][r] += __builtin_amdgcn_exp2f(s[r] * ES);
            }
        }
    }
    #pragma unroll
    for (int qt = 0; qt < 2; ++qt)
        #pragma unroll
        for (int m = 0; m < 4; ++m)
            #pragma unroll
            for (int r = 0; r < 4; ++r) {
                float v = zs[qt][m][r];
                v += __shfl_xor(v, 1);
                v += __shfl_xor(v, 2);
                v += __shfl_xor(v, 4);
                v += __shfl_xor(v, 8);
                zs[qt][m][r] = v;
            }
    __shared__ float Zp[4][2][4][4][4];   // [w][qt][lg][m][r]
    if (lc == 0) {
        #pragma unroll
        for (int qt = 0; qt < 2; ++qt)
            #pragma unroll
            for (int m = 0; m < 4; ++m)
                #pragma unroll
                for (int r = 0; r < 4; ++r) Zp[w][qt][lg][m][r] = zs[qt][m][r];
    }
    __syncthreads();
    if (tid < 128) {
        const int q = tid >> 2, m = tid & 3;
        const int qt = q >> 4, g = (q >> 2) & 3, r = q & 3;
        float z = Zp[0][qt][g][m][r] + Zp[1][qt][g][m][r]
                + Zp[2][qt][g][m][r] + Zp[3][qt][g][m][r];
        Zh[(((size_t)kh * NB + b) * LL + qb + q) * NMIX + m] = z;
    }
}

// ---------------------------------------------------------------------------
// Kernel A (v11): QK + softmax + attn write ONLY. No PV, no V.
// grid 256 = b(8, bid&7) x qt(32, 64 q-rows); 1024 thr / 16 waves.
// waves = wq(2: 32q each) x wk(8: 16k slice of 128k window) -> K LDS reads 2x.
// Per 128k window: QK -> E(bf16, swizzled) ; bar1 ; gl16 next K + E->attn
// f32 nt_store ; bar2 (drains gl16).
__launch_bounds__(1024, 4)
__global__ void qk_attn(const float* __restrict__ query,
                        const unsigned short* __restrict__ Kp,
                        const float* __restrict__ Zh,
                        const float* __restrict__ piAll,
                        float* __restrict__ attn) {
    const int bid = blockIdx.x;
    const int b   = bid & 7;             // XCD affinity
    const int qt  = bid >> 3;            // 0..31
    const int qb  = qt * 64;
    const int tid = threadIdx.x;
    const int w = tid >> 6, lane = tid & 63, lg = lane >> 4, lc = lane & 15;
    const int wq = w >> 3, wk = w & 7;

    __shared__ __align__(16) unsigned short Ks[64 * 512];   // 64KB: one 128k window
    __shared__ __align__(16) unsigned short E[64 * EPA];    // 17.4KB

    // Q A-fragments for this wave's 32 q-rows (2 x 16): A[row=q=lc][ch]
    bf16x8 qf[2][4][2];
    hoist_q2(query, b, qb + wq * 32, lg, lc, qf);

    // C[qt2][m][r] = log2(pi_m / Z) for q = qb + wq*32 + qt2*16 + lg*4 + r
    float C[2][4][4];
    #pragma unroll
    for (int qt2 = 0; qt2 < 2; ++qt2)
        #pragma unroll
        for (int r = 0; r < 4; ++r) {
            const int q = qb + wq * 32 + qt2 * 16 + lg * 4 + r;
            #pragma unroll
            for (int m = 0; m < 4; ++m) {
                float z = Zh[((size_t)b * LL + q) * NMIX + m]
                        + Zh[((size_t)(NB + b) * LL + q) * NMIX + m];
                C[qt2][m][r] = __log2f(piAll[b * NMIX + m] / z);
            }
        }

    const unsigned short* kpB = Kp + (size_t)b * 128 * 8 * 512;
    const float ES = 0.09016844005555896f;   // log2(e)/16

    // store-phase indexing (swizzle: XOR col bit4 with row bit3)
    const int erow  = tid >> 4;                       // 0..63
    const int ec0   = (tid & 15) * 8;                 // 0..120
    const int ecsw  = ec0 ^ (((erow >> 3) & 1) << 4);
    float* arow = attn + ((size_t)b * LL + qb + erow) * LL + ec0;

    // prologue: stage window 0 (64 frags, wave stages 4)
    #pragma unroll
    for (int s = 0; s < 4; ++s)
        gl16(kpB + (size_t)(w * 4 + s) * 512 + lane * 8, &Ks[(w * 4 + s) * 512]);
    __syncthreads();

    for (int j = 0; j < 16; ++j) {
        // ---- QK: wave (wq,wk) -> 32q x 16k from LDS K frags ----
        {
            const unsigned short* kf = &Ks[(wk * 8) * 512 + lane * 8];
            float av[2][4];
            #pragma unroll
            for (int qt2 = 0; qt2 < 2; ++qt2)
                #pragma unroll
                for (int r = 0; r < 4; ++r) av[qt2][r] = 0.f;
            #pragma unroll
            for (int m = 0; m < 4; ++m) {
                bf16x8 k0 = *reinterpret_cast<const bf16x8*>(kf + (m * 2 + 0) * 512);
                bf16x8 k1 = *reinterpret_cast<const bf16x8*>(kf + (m * 2 + 1) * 512);
                #pragma unroll
                for (int qt2 = 0; qt2 < 2; ++qt2) {
                    f32x4 s = {0.f, 0.f, 0.f, 0.f};
                    s = __builtin_amdgcn_mfma_f32_16x16x32_bf16(qf[qt2][m][0], k0, s, 0, 0, 0);
                    s = __builtin_amdgcn_mfma_f32_16x16x32_bf16(qf[qt2][m][1], k1, s, 0, 0, 0);
                    #pragma unroll
                    for (int r = 0; r < 4; ++r)
                        av[qt2][r] += __builtin_amdgcn_exp2f(fmaf(s[r], ES, C[qt2][m][r]));
                }
            }
            #pragma unroll
            for (int qt2 = 0; qt2 < 2; ++qt2)
                #pragma unroll
                for (int r = 0; r < 4; ++r) {
                    const int row = wq * 32 + qt2 * 16 + lg * 4 + r;
                    const int col = (wk * 16 + lc) ^ (((row >> 3) & 1) << 4);
                    E[row * EPA + col] = f2bf(av[qt2][r]);
                }
        }
        __syncthreads();   // bar1: E complete; all K reads of this window done

        // stage next window into Ks (overwrite safe; drained by bar2)
        if (j < 15) {
            #pragma unroll
            for (int s = 0; s < 4; ++s)
                gl16(kpB + (size_t)((j + 1) * 64 + w * 4 + s) * 512 + lane * 8,
                     &Ks[(w * 4 + s) * 512]);
        }

        // ---- attn store: 64q x 128k, f32 nontemporal (2x f32x4 per thread) ----
        {
            bf16x8 e = *reinterpret_cast<const bf16x8*>(&E[erow * EPA + ecsw]);
            f32x4 f0, f1;
            #pragma unroll
            for (int i = 0; i < 4; ++i) {
                f0[i] = bf2f((unsigned short)e[i]);
                f1[i] = bf2f((unsigned short)e[i + 4]);
            }
            nt_store4(arow + j * 128, f0);
            nt_store4(arow + j * 128 + 4, f1);
        }
        __syncthreads();   // bar2: gl16 drained; E free for next window
    }
}

// ---------------------------------------------------------------------------
// Kernel B (v11): pure PV GEMM  out[b,q,v] = sum_k attn[b,q,k] * V[b,v,k].
// grid 256 = b(8, bid&7) x qt(32, 64 q-rows); 1024 thr / 16 waves.
// waves = wq(4: 16q) x wv(4: 64v). A-frags DIRECT from global attn (L1/L2
// absorbs the 4x wv re-read); V via gl16 double-buffered LDS (stride-1,
// conflict-free); one barrier per 32k step.
__launch_bounds__(1024, 4)
__global__ void pv_gemm(const float* __restrict__ attn,
                        const unsigned short* __restrict__ Vp,
                        float* __restrict__ out) {
    const int bid = blockIdx.x;
    const int b   = bid & 7;             // XCD affinity
    const int qt  = bid >> 3;            // 0..31
    const int qb  = qt * 64;
    const int tid = threadIdx.x;
    const int w = tid >> 6, lane = tid & 63, lg = lane >> 4, lc = lane & 15;
    const int wq = w >> 2, wv = w & 3;

    __shared__ __align__(16) unsigned short Vs[2][16 * 512];   // 2 x 16KB

    const unsigned short* vpB = Vp + (size_t)b * 64 * 16 * 512;
    const float* aRow = attn + ((size_t)b * LL + qb + wq * 16 + lc) * LL + lg * 8;

    f32x4 oacc[4];
    #pragma unroll
    for (int vj = 0; vj < 4; ++vj) oacc[vj] = (f32x4){0.f, 0.f, 0.f, 0.f};

    // prologue: stage V step 0 (16KB; wave stages 1KB)
    gl16(vpB + (size_t)w * 512 + lane * 8, &Vs[0][w * 512]);
    __syncthreads();

    for (int step = 0; step < 64; ++step) {
        const int cur = step & 1;
        if (step < 63)
            gl16(vpB + (size_t)(step + 1) * 8192 + w * 512 + lane * 8,
                 &Vs[cur ^ 1][w * 512]);

        // A-frag direct from global (8 f32 per lane -> bf16x8, exact re-round)
        float4 a0 = *reinterpret_cast<const float4*>(aRow + (size_t)step * 32);
        float4 a1 = *reinterpret_cast<const float4*>(aRow + (size_t)step * 32 + 4);
        unsigned int p0 = cvtpk_bf16(a0.x, a0.y);
        unsigned int p1 = cvtpk_bf16(a0.z, a0.w);
        unsigned int p2 = cvtpk_bf16(a1.x, a1.y);
        unsigned int p3 = cvtpk_bf16(a1.z, a1.w);
        bf16x8 ea;
        ea[0] = (short)(p0 & 0xFFFF); ea[1] = (short)(p0 >> 16);
        ea[2] = (short)(p1 & 0xFFFF); ea[3] = (short)(p1 >> 16);
        ea[4] = (short)(p2 & 0xFFFF); ea[5] = (short)(p2 >> 16);
        ea[6] = (short)(p3 & 0xFFFF); ea[7] = (short)(p3 >> 16);

        // PV: 4 vj fragments of this wave's 64v slice
        #pragma unroll
        for (int vj = 0; vj < 4; ++vj) {
            bf16x8 vf = *reinterpret_cast<const bf16x8*>(
                &Vs[cur][(wv * 4 + vj) * 512 + lane * 8]);
            oacc[vj] = __builtin_amdgcn_mfma_f32_16x16x32_bf16(ea, vf, oacc[vj], 0, 0, 0);
        }
        __syncthreads();   // Vs[cur] reads done; gl16(next) drained
    }

    // out: q = qb + wq*16 + lg*4 + r ; v = wv*64 + vj*16 + lc
    #pragma unroll
    for (int vj = 0; vj < 4; ++vj)
        #pragma unroll
        for (int r = 0; r < 4; ++r)
            out[((size_t)b * LL + qb + wq * 16 + lg * 4 + r) * DV
                + wv * 64 + vj * 16 + lc] = oacc[vj][r];
}

// ---------------------------------------------------------------------------
extern "C" void kernel_launch(void* const* d_in, const int* in_sizes, int n_in,
                              void* d_out, int out_size, void* d_ws, size_t ws_size,
                              hipStream_t stream) {
    const float* query   = (const float*)d_in[0];   // (8, 256, 2048)
    const float* key     = (const float*)d_in[1];   // (8, 256, 2048)
    const float* value   = (const float*)d_in[2];   // (8, 256, 2048)
    const float* weights = (const float*)d_in[3];   // (4, 256)

    float* out  = (float*)d_out;                    // (8, 2048, 256)
    float* attn = out + (size_t)NB * LL * DV;       // (8, 2048, 2048)

    // workspace (~17.3 MB)
    char* ws = (char*)d_ws;
    float* avg = (float*)ws;                              // 8KB
    float* pi  = (float*)(ws + 8192);                     // 32B
    float* Zh  = (float*)(ws + 12288);                    // 512KB
    unsigned short* Kp = (unsigned short*)(ws + 536576);  // 8.4MB packed K frags
    unsigned short* Vp = Kp + (size_t)NB * LL * DK;       // 8.4MB packed V frags

    avg_k<<<NB * DK, 256, 0, stream>>>(query, avg);
    pi_k<<<NB, 64, 0, stream>>>(weights, avg, pi);
    pack_kv<<<4096, 256, 0, stream>>>(key, value, Kp, Vp);
    zsum_k<<<1024, 256, 0, stream>>>(query, Kp, Zh);
    qk_attn<<<256, 1024, 0, stream>>>(query, Kp, Zh, pi, attn);
    pv_gemm<<<256, 1024, 0, stream>>>(attn, Vp, out);
}

// Round 12
// 183.967 us; speedup vs baseline: 1.2945x; 1.2945x over previous
//
#include <hip/hip_runtime.h>
#include <hip/hip_bf16.h>

// Problem constants (fixed by setup_inputs)
#define NB   8      // batch
#define DK   256    // dk (4 mixtures x 64)
#define LL   2048   // Lq == Lk
#define DV   256    // dv
#define NMIX 4
#define EPA  136    // qk_attn E pitch (shorts)
#define AP   68     // pv_gemm A-tile pitch (shorts): bank stride 2 -> <=2-way

typedef __attribute__((ext_vector_type(8))) short bf16x8;
typedef __attribute__((ext_vector_type(4))) short bf16x4;
typedef __attribute__((ext_vector_type(4))) float f32x4;

__device__ __forceinline__ unsigned short f2bf(float x) {
    unsigned int u = __float_as_uint(x);
    return (unsigned short)((u + 0x7FFFu + ((u >> 16) & 1u)) >> 16);  // RNE
}
__device__ __forceinline__ float bf2f(unsigned short u) {
    return __uint_as_float(((unsigned int)u) << 16);
}
// async global->LDS: per-lane global src; LDS dest = uniform base + lane*16B
__device__ __forceinline__ void gl16(const unsigned short* g, unsigned short* l) {
    __builtin_amdgcn_global_load_lds(
        (const __attribute__((address_space(1))) unsigned int*)(const void*)g,
        (__attribute__((address_space(3))) unsigned int*)(void*)l, 16, 0, 0);
}

// ---------------------------------------------------------------------------
// Pack K and V into exact MFMA B-operand fragment order (1KB per wave-frag).
// Kp[((b*128+kt16)*8+cc)*512 + lane*8+i] = bf16(K[b][cc*32+lg*8+i][kt16*16+lc])
// Vp[((b*64+kt32)*16+vj)*512 + lane*8+i] = bf16(V[b][vj*16+lc][kt32*32+lg*8+i])
__global__ void pack_kv(const float* __restrict__ key,
                        const float* __restrict__ value,
                        unsigned short* __restrict__ Kp,
                        unsigned short* __restrict__ Vp) {
    const int gid0 = blockIdx.x * 256 + threadIdx.x;
    if (blockIdx.x < 2048) {
        const int gid = gid0;                 // 0 .. 524287
        const int lane = gid & 63;
        const int cc   = (gid >> 6) & 7;      // 32-ch chunk
        const int kt   = (gid >> 9) & 127;    // 16-k tile
        const int b    = gid >> 16;
        const int lg = lane >> 4, lc = lane & 15;
        const float* src = key + ((size_t)b * DK + cc * 32 + lg * 8) * LL + kt * 16 + lc;
        bf16x8 o;
        #pragma unroll
        for (int i = 0; i < 8; ++i) o[i] = (short)f2bf(src[(size_t)i * LL]);
        *reinterpret_cast<bf16x8*>(Kp + (size_t)gid * 8) = o;
    } else {
        const int gid = gid0 - 2048 * 256;    // 0 .. 524287
        const int lane = gid & 63;
        const int vj   = (gid >> 6) & 15;
        const int kt   = (gid >> 10) & 63;    // 32-k tile
        const int b    = gid >> 16;
        const int lg = lane >> 4, lc = lane & 15;
        const float* src = value + ((size_t)b * DV + vj * 16 + lc) * LL + kt * 32 + lg * 8;
        float4 v0 = *reinterpret_cast<const float4*>(src);
        float4 v1 = *reinterpret_cast<const float4*>(src + 4);
        bf16x8 o;
        o[0] = (short)f2bf(v0.x); o[1] = (short)f2bf(v0.y);
        o[2] = (short)f2bf(v0.z); o[3] = (short)f2bf(v0.w);
        o[4] = (short)f2bf(v1.x); o[5] = (short)f2bf(v1.y);
        o[6] = (short)f2bf(v1.z); o[7] = (short)f2bf(v1.w);
        *reinterpret_cast<bf16x8*>(Vp + (size_t)gid * 8) = o;
    }
}

// avg_query: one block per (b*DK + d) row, mean over LL
__global__ void avg_k(const float* __restrict__ q, float* __restrict__ avg) {
    const int row = blockIdx.x;
    const float* p = q + (size_t)row * LL;
    float s = 0.f;
    for (int i = threadIdx.x; i < LL; i += 256) s += p[i];
    #pragma unroll
    for (int off = 32; off >= 1; off >>= 1) s += __shfl_down(s, off);
    __shared__ float ps[4];
    if ((threadIdx.x & 63) == 0) ps[threadIdx.x >> 6] = s;
    __syncthreads();
    if (threadIdx.x == 0)
        avg[row] = (ps[0] + ps[1] + ps[2] + ps[3]) * (1.0f / LL);
}

// pi = softmax_m( w[m,:] . avg[b,:] ) ; one wave per b
__global__ void pi_k(const float* __restrict__ wgt, const float* __restrict__ avg,
                     float* __restrict__ piOut) {
    const int b = blockIdx.x;
    const int l = threadIdx.x;   // 0..63
    float part[NMIX] = {0.f, 0.f, 0.f, 0.f};
    for (int d = l; d < DK; d += 64) {
        float a = avg[b * DK + d];
        #pragma unroll
        for (int m = 0; m < NMIX; ++m) part[m] += wgt[m * DK + d] * a;
    }
    #pragma unroll
    for (int off = 1; off < 64; off <<= 1) {
        #pragma unroll
        for (int m = 0; m < NMIX; ++m) part[m] += __shfl_xor(part[m], off);
    }
    float mx = fmaxf(fmaxf(part[0], part[1]), fmaxf(part[2], part[3]));
    float e0 = __expf(part[0] - mx), e1 = __expf(part[1] - mx);
    float e2 = __expf(part[2] - mx), e3 = __expf(part[3] - mx);
    float z = e0 + e1 + e2 + e3;
    float mine = (l == 0) ? e0 : (l == 1) ? e1 : (l == 2) ? e2 : e3;
    if (l < NMIX) piOut[b * NMIX + l] = mine / z;
}

// ---------------------------------------------------------------------------
// Q A-fragment hoist from raw f32 query: A[row=q=lc][ch=lg*8+i]; qf[qt][m][c].
__device__ __forceinline__ void hoist_q2(const float* __restrict__ query,
                                         int b, int qrow0, int lg, int lc,
                                         bf16x8 qf[2][4][2]) {
    #pragma unroll
    for (int qt = 0; qt < 2; ++qt)
        #pragma unroll
        for (int m = 0; m < 4; ++m)
            #pragma unroll
            for (int c = 0; c < 2; ++c) {
                const float* src = query + ((size_t)b * DK + m * 64 + c * 32 + lg * 8) * LL
                                   + qrow0 + qt * 16 + lc;
                bf16x8 f;
                #pragma unroll
                for (int i = 0; i < 8; ++i) f[i] = (short)f2bf(src[(size_t)i * LL]);
                qf[qt][m][c] = f;
            }
}

// ---------------------------------------------------------------------------
// Z pre-pass (unchanged, known-good):
// Zh[kh][b][q][m] = sum_{k in half} exp2(S*ES)
__launch_bounds__(256, 4)
__global__ void zsum_k(const float* __restrict__ query,
                       const unsigned short* __restrict__ Kp,
                       float* __restrict__ Zh) {
    const int bid = blockIdx.x;
    const int b    = bid & 7;             // XCD affinity
    const int qt64 = (bid >> 3) & 63;
    const int kh   = bid >> 9;
    const int qb   = qt64 * 32;
    const int tid  = threadIdx.x;
    const int w = tid >> 6, lane = tid & 63, lg = lane >> 4, lc = lane & 15;

    bf16x8 qf[2][4][2];
    hoist_q2(query, b, qb, lg, lc, qf);

    const unsigned short* kpB = Kp + (size_t)b * 128 * 8 * 512;
    const float ES = 0.09016844005555896f;   // log2(e)/16

    float zs[2][4][4];
    #pragma unroll
    for (int qt = 0; qt < 2; ++qt)
        #pragma unroll
        for (int m = 0; m < 4; ++m)
            #pragma unroll
            for (int r = 0; r < 4; ++r) zs[qt][m][r] = 0.f;

    for (int t = 0; t < 16; ++t) {
        const int ktile = kh * 64 + w * 16 + t;
        const unsigned short* kp = kpB + (size_t)ktile * 8 * 512 + lane * 8;
        #pragma unroll
        for (int m = 0; m < 4; ++m) {
            bf16x8 k0 = *reinterpret_cast<const bf16x8*>(kp + (m * 2 + 0) * 512);
            bf16x8 k1 = *reinterpret_cast<const bf16x8*>(kp + (m * 2 + 1) * 512);
            #pragma unroll
            for (int qt = 0; qt < 2; ++qt) {
                f32x4 s = {0.f, 0.f, 0.f, 0.f};
                s = __builtin_amdgcn_mfma_f32_16x16x32_bf16(qf[qt][m][0], k0, s, 0, 0, 0);
                s = __builtin_amdgcn_mfma_f32_16x16x32_bf16(qf[qt][m][1], k1, s, 0, 0, 0);
                #pragma unroll
                for (int r = 0; r < 4; ++r)
                    zs[qt][m][r] += __builtin_amdgcn_exp2f(s[r] * ES);
            }
        }
    }
    #pragma unroll
    for (int qt = 0; qt < 2; ++qt)
        #pragma unroll
        for (int m = 0; m < 4; ++m)
            #pragma unroll
            for (int r = 0; r < 4; ++r) {
                float v = zs[qt][m][r];
                v += __shfl_xor(v, 1);
                v += __shfl_xor(v, 2);
                v += __shfl_xor(v, 4);
                v += __shfl_xor(v, 8);
                zs[qt][m][r] = v;
            }
    __shared__ float Zp[4][2][4][4][4];   // [w][qt][lg][m][r]
    if (lc == 0) {
        #pragma unroll
        for (int qt = 0; qt < 2; ++qt)
            #pragma unroll
            for (int m = 0; m < 4; ++m)
                #pragma unroll
                for (int r = 0; r < 4; ++r) Zp[w][qt][lg][m][r] = zs[qt][m][r];
    }
    __syncthreads();
    if (tid < 128) {
        const int q = tid >> 2, m = tid & 3;
        const int qt = q >> 4, g = (q >> 2) & 3, r = q & 3;
        float z = Zp[0][qt][g][m][r] + Zp[1][qt][g][m][r]
                + Zp[2][qt][g][m][r] + Zp[3][qt][g][m][r];
        Zh[(((size_t)kh * NB + b) * LL + qb + q) * NMIX + m] = z;
    }
}

// ---------------------------------------------------------------------------
// Kernel A (v12): QK + softmax + attn write. K stage DOUBLE-buffered; stage
// for window j+1 issued BEFORE window j's QK (flies under compute).
// grid 256 = b(8, bid&7) x qt(32, 64 q-rows); 1024 thr / 16 waves.
// waves = wq(2: 32q each) x wk(8: 16k slice of 128k window).
// attn stored with REGULAR stores (stays L3-resident for pv_gemm read-back).
__launch_bounds__(1024, 4)
__global__ void qk_attn(const float* __restrict__ query,
                        const unsigned short* __restrict__ Kp,
                        const float* __restrict__ Zh,
                        const float* __restrict__ piAll,
                        float* __restrict__ attn) {
    const int bid = blockIdx.x;
    const int b   = bid & 7;             // XCD affinity
    const int qt  = bid >> 3;            // 0..31
    const int qb  = qt * 64;
    const int tid = threadIdx.x;
    const int w = tid >> 6, lane = tid & 63, lg = lane >> 4, lc = lane & 15;
    const int wq = w >> 3, wk = w & 7;

    __shared__ __align__(16) unsigned short Ks[2][64 * 512];  // 2 x 64KB
    __shared__ __align__(16) unsigned short E[64 * EPA];      // 17.4KB

    // Q A-fragments for this wave's 32 q-rows (2 x 16): A[row=q=lc][ch]
    bf16x8 qf[2][4][2];
    hoist_q2(query, b, qb + wq * 32, lg, lc, qf);

    // C[qt2][m][r] = log2(pi_m / Z) for q = qb + wq*32 + qt2*16 + lg*4 + r
    float C[2][4][4];
    #pragma unroll
    for (int qt2 = 0; qt2 < 2; ++qt2)
        #pragma unroll
        for (int r = 0; r < 4; ++r) {
            const int q = qb + wq * 32 + qt2 * 16 + lg * 4 + r;
            #pragma unroll
            for (int m = 0; m < 4; ++m) {
                float z = Zh[((size_t)b * LL + q) * NMIX + m]
                        + Zh[((size_t)(NB + b) * LL + q) * NMIX + m];
                C[qt2][m][r] = __log2f(piAll[b * NMIX + m] / z);
            }
        }

    const unsigned short* kpB = Kp + (size_t)b * 128 * 8 * 512;
    const float ES = 0.09016844005555896f;   // log2(e)/16

    // store-phase indexing (swizzle: XOR col bit4 with row bit3)
    const int erow  = tid >> 4;                       // 0..63
    const int ec0   = (tid & 15) * 8;                 // 0..120
    const int ecsw  = ec0 ^ (((erow >> 3) & 1) << 4);
    float* arow = attn + ((size_t)b * LL + qb + erow) * LL + ec0;

    // prologue: stage window 0 into Ks[0]
    #pragma unroll
    for (int s = 0; s < 4; ++s)
        gl16(kpB + (size_t)(w * 4 + s) * 512 + lane * 8, &Ks[0][(w * 4 + s) * 512]);
    __syncthreads();

    for (int j = 0; j < 16; ++j) {
        const int buf = j & 1;
        // stage next window FIRST: flies under QK; Ks[buf^1]'s readers all
        // passed bar2(j-1) (they are at window j). Drained at bar1(j).
        if (j < 15) {
            #pragma unroll
            for (int s = 0; s < 4; ++s)
                gl16(kpB + (size_t)((j + 1) * 64 + w * 4 + s) * 512 + lane * 8,
                     &Ks[buf ^ 1][(w * 4 + s) * 512]);
        }

        // ---- QK: wave (wq,wk) -> 32q x 16k from LDS K frags ----
        {
            const unsigned short* kf = &Ks[buf][(wk * 8) * 512 + lane * 8];
            float av[2][4];
            #pragma unroll
            for (int qt2 = 0; qt2 < 2; ++qt2)
                #pragma unroll
                for (int r = 0; r < 4; ++r) av[qt2][r] = 0.f;
            #pragma unroll
            for (int m = 0; m < 4; ++m) {
                bf16x8 k0 = *reinterpret_cast<const bf16x8*>(kf + (m * 2 + 0) * 512);
                bf16x8 k1 = *reinterpret_cast<const bf16x8*>(kf + (m * 2 + 1) * 512);
                #pragma unroll
                for (int qt2 = 0; qt2 < 2; ++qt2) {
                    f32x4 s = {0.f, 0.f, 0.f, 0.f};
                    s = __builtin_amdgcn_mfma_f32_16x16x32_bf16(qf[qt2][m][0], k0, s, 0, 0, 0);
                    s = __builtin_amdgcn_mfma_f32_16x16x32_bf16(qf[qt2][m][1], k1, s, 0, 0, 0);
                    #pragma unroll
                    for (int r = 0; r < 4; ++r)
                        av[qt2][r] += __builtin_amdgcn_exp2f(fmaf(s[r], ES, C[qt2][m][r]));
                }
            }
            #pragma unroll
            for (int qt2 = 0; qt2 < 2; ++qt2)
                #pragma unroll
                for (int r = 0; r < 4; ++r) {
                    const int row = wq * 32 + qt2 * 16 + lg * 4 + r;
                    const int col = (wk * 16 + lc) ^ (((row >> 3) & 1) << 4);
                    E[row * EPA + col] = f2bf(av[qt2][r]);
                }
        }
        __syncthreads();   // bar1: E complete; this wave's gl16s drained

        // ---- attn store: 64q x 128k, regular stores (keep in L3) ----
        {
            bf16x8 e = *reinterpret_cast<const bf16x8*>(&E[erow * EPA + ecsw]);
            f32x4 f0, f1;
            #pragma unroll
            for (int i = 0; i < 4; ++i) {
                f0[i] = bf2f((unsigned short)e[i]);
                f1[i] = bf2f((unsigned short)e[i + 4]);
            }
            *reinterpret_cast<f32x4*>(arow + j * 128)     = f0;
            *reinterpret_cast<f32x4*>(arow + j * 128 + 4) = f1;
        }
        __syncthreads();   // bar2: E reads done -> E reusable next window
    }
}

// ---------------------------------------------------------------------------
// Kernel B (v12): PV GEMM with coalesced A. Per 64k window:
//   bar1; stage V(j+1) (gl16 dbuf); write Asd[j&1] <- cvt(aReg) (LDS repack)
//   bar2; issue aReg = load A(j+1) (coalesced f32x4/thread); compute 8 MFMA.
// grid 256 = b(8, bid&7) x qt(32, 64 q-rows); 1024 thr / 16 waves
// (wq4: 16q x wv4: 64v).
__launch_bounds__(1024, 4)
__global__ void pv_gemm(const float* __restrict__ attn,
                        const unsigned short* __restrict__ Vp,
                        float* __restrict__ out) {
    const int bid = blockIdx.x;
    const int b   = bid & 7;             // XCD affinity
    const int qt  = bid >> 3;            // 0..31
    const int qb  = qt * 64;
    const int tid = threadIdx.x;
    const int w = tid >> 6, lane = tid & 63, lg = lane >> 4, lc = lane & 15;
    const int wq = w >> 2, wv = w & 3;

    __shared__ __align__(16) unsigned short Vs[2][32 * 512];  // 2 x 32KB
    __shared__ __align__(16) unsigned short Asd[2][64 * AP];  // 2 x 8.5KB

    const unsigned short* vpB = Vp + (size_t)b * 64 * 16 * 512;
    // coalesced A-tile pointer: thread reads row qb+(tid>>4), cols (tid&15)*4
    const float* aSrc = attn + ((size_t)b * LL + qb + (tid >> 4)) * LL + (tid & 15) * 4;
    const int aRow = tid >> 4, aCol = (tid & 15) * 4;

    f32x4 oacc[4];
    #pragma unroll
    for (int vj = 0; vj < 4; ++vj) oacc[vj] = (f32x4){0.f, 0.f, 0.f, 0.f};

    // prologue: stage V window 0; load A window 0
    #pragma unroll
    for (int r = 0; r < 2; ++r)
        gl16(vpB + (size_t)(w * 2 + r) * 512 + lane * 8, &Vs[0][(w * 2 + r) * 512]);
    f32x4 aReg = *reinterpret_cast<const f32x4*>(aSrc);

    for (int j = 0; j < 32; ++j) {
        const int cur = j & 1;
        __syncthreads();   // bar1: V(j) staged (all gl16 drained); Asd[cur] free
        if (j < 31) {
            #pragma unroll
            for (int r = 0; r < 2; ++r)
                gl16(vpB + (size_t)((j + 1) * 32 + w * 2 + r) * 512 + lane * 8,
                     &Vs[cur ^ 1][(w * 2 + r) * 512]);
        }
        // repack A: f32x4 -> 4 bf16 -> Asd[cur]
        {
            bf16x4 p;
            p[0] = (short)f2bf(aReg[0]); p[1] = (short)f2bf(aReg[1]);
            p[2] = (short)f2bf(aReg[2]); p[3] = (short)f2bf(aReg[3]);
            *reinterpret_cast<bf16x4*>(&Asd[cur][aRow * AP + aCol]) = p;
        }
        __syncthreads();   // bar2: Asd[cur] complete

        // prefetch next A tile (flies under compute)
        if (j < 31) aReg = *reinterpret_cast<const f32x4*>(aSrc + (size_t)(j + 1) * 64);

        // ---- compute: wave (wq,wv): 16q x 64v over this 64k window ----
        #pragma unroll
        for (int kt = 0; kt < 2; ++kt) {
            bf16x8 ea = *reinterpret_cast<const bf16x8*>(
                &Asd[cur][(wq * 16 + lc) * AP + kt * 32 + lg * 8]);
            #pragma unroll
            for (int vj = 0; vj < 4; ++vj) {
                bf16x8 vf = *reinterpret_cast<const bf16x8*>(
                    &Vs[cur][(kt * 16 + wv * 4 + vj) * 512 + lane * 8]);
                oacc[vj] = __builtin_amdgcn_mfma_f32_16x16x32_bf16(ea, vf, oacc[vj], 0, 0, 0);
            }
        }
    }

    // out: q = qb + wq*16 + lg*4 + r ; v = wv*64 + vj*16 + lc
    #pragma unroll
    for (int vj = 0; vj < 4; ++vj)
        #pragma unroll
        for (int r = 0; r < 4; ++r)
            out[((size_t)b * LL + qb + wq * 16 + lg * 4 + r) * DV
                + wv * 64 + vj * 16 + lc] = oacc[vj][r];
}

// ---------------------------------------------------------------------------
extern "C" void kernel_launch(void* const* d_in, const int* in_sizes, int n_in,
                              void* d_out, int out_size, void* d_ws, size_t ws_size,
                              hipStream_t stream) {
    const float* query   = (const float*)d_in[0];   // (8, 256, 2048)
    const float* key     = (const float*)d_in[1];   // (8, 256, 2048)
    const float* value   = (const float*)d_in[2];   // (8, 256, 2048)
    const float* weights = (const float*)d_in[3];   // (4, 256)

    float* out  = (float*)d_out;                    // (8, 2048, 256)
    float* attn = out + (size_t)NB * LL * DV;       // (8, 2048, 2048)

    // workspace (~17.3 MB)
    char* ws = (char*)d_ws;
    float* avg = (float*)ws;                              // 8KB
    float* pi  = (float*)(ws + 8192);                     // 32B
    float* Zh  = (float*)(ws + 12288);                    // 512KB
    unsigned short* Kp = (unsigned short*)(ws + 536576);  // 8.4MB packed K frags
    unsigned short* Vp = Kp + (size_t)NB * LL * DK;       // 8.4MB packed V frags

    avg_k<<<NB * DK, 256, 0, stream>>>(query, avg);
    pi_k<<<NB, 64, 0, stream>>>(weights, avg, pi);
    pack_kv<<<4096, 256, 0, stream>>>(key, value, Kp, Vp);
    zsum_k<<<1024, 256, 0, stream>>>(query, Kp, Zh);
    qk_attn<<<256, 1024, 0, stream>>>(query, Kp, Zh, pi, attn);
    pv_gemm<<<256, 1024, 0, stream>>>(attn, Vp, out);
}

// Round 13
// 126.022 us; speedup vs baseline: 1.8897x; 1.4598x over previous
//
#include <hip/hip_runtime.h>
#include <hip/hip_bf16.h>

// Problem constants (fixed by setup_inputs)
#define NB   8      // batch
#define DK   256    // dk (4 mixtures x 64)
#define LL   2048   // Lq == Lk
#define DV   256    // dv
#define NMIX 4

typedef __attribute__((ext_vector_type(8))) short bf16x8;
typedef __attribute__((ext_vector_type(4))) short bf16x4;
typedef __attribute__((ext_vector_type(4))) float f32x4;

__device__ __forceinline__ unsigned short f2bf(float x) {
    unsigned int u = __float_as_uint(x);
    return (unsigned short)((u + 0x7FFFu + ((u >> 16) & 1u)) >> 16);  // RNE
}
__device__ __forceinline__ float bf2f(unsigned short u) {
    return __uint_as_float(((unsigned int)u) << 16);
}
__device__ __forceinline__ void nt_store4(float* p, f32x4 v) {
    __builtin_nontemporal_store(v, reinterpret_cast<f32x4*>(p));
}
// async global->LDS: per-lane global src; LDS dest = uniform base + lane*16B
__device__ __forceinline__ void gl16(const unsigned short* g, unsigned short* l) {
    __builtin_amdgcn_global_load_lds(
        (const __attribute__((address_space(1))) unsigned int*)(const void*)g,
        (__attribute__((address_space(3))) unsigned int*)(void*)l, 16, 0, 0);
}

// ---------------------------------------------------------------------------
// Pack K and V into exact MFMA B-operand fragment order (1KB per wave-frag).
// Kp[((b*128+kt16)*8+cc)*512 + lane*8+i] = bf16(K[b][cc*32+lg*8+i][kt16*16+lc])
// Vp[((b*64+kt32)*16+vj)*512 + lane*8+i] = bf16(V[b][vj*16+lc][kt32*32+lg*8+i])
__global__ void pack_kv(const float* __restrict__ key,
                        const float* __restrict__ value,
                        unsigned short* __restrict__ Kp,
                        unsigned short* __restrict__ Vp) {
    const int gid0 = blockIdx.x * 256 + threadIdx.x;
    if (blockIdx.x < 2048) {
        const int gid = gid0;                 // 0 .. 524287
        const int lane = gid & 63;
        const int cc   = (gid >> 6) & 7;      // 32-ch chunk
        const int kt   = (gid >> 9) & 127;    // 16-k tile
        const int b    = gid >> 16;
        const int lg = lane >> 4, lc = lane & 15;
        const float* src = key + ((size_t)b * DK + cc * 32 + lg * 8) * LL + kt * 16 + lc;
        bf16x8 o;
        #pragma unroll
        for (int i = 0; i < 8; ++i) o[i] = (short)f2bf(src[(size_t)i * LL]);
        *reinterpret_cast<bf16x8*>(Kp + (size_t)gid * 8) = o;
    } else {
        const int gid = gid0 - 2048 * 256;    // 0 .. 524287
        const int lane = gid & 63;
        const int vj   = (gid >> 6) & 15;
        const int kt   = (gid >> 10) & 63;    // 32-k tile
        const int b    = gid >> 16;
        const int lg = lane >> 4, lc = lane & 15;
        const float* src = value + ((size_t)b * DV + vj * 16 + lc) * LL + kt * 32 + lg * 8;
        float4 v0 = *reinterpret_cast<const float4*>(src);
        float4 v1 = *reinterpret_cast<const float4*>(src + 4);
        bf16x8 o;
        o[0] = (short)f2bf(v0.x); o[1] = (short)f2bf(v0.y);
        o[2] = (short)f2bf(v0.z); o[3] = (short)f2bf(v0.w);
        o[4] = (short)f2bf(v1.x); o[5] = (short)f2bf(v1.y);
        o[6] = (short)f2bf(v1.z); o[7] = (short)f2bf(v1.w);
        *reinterpret_cast<bf16x8*>(Vp + (size_t)gid * 8) = o;
    }
}

// avg_query: one block per (b*DK + d) row, mean over LL
__global__ void avg_k(const float* __restrict__ q, float* __restrict__ avg) {
    const int row = blockIdx.x;
    const float* p = q + (size_t)row * LL;
    float s = 0.f;
    for (int i = threadIdx.x; i < LL; i += 256) s += p[i];
    #pragma unroll
    for (int off = 32; off >= 1; off >>= 1) s += __shfl_down(s, off);
    __shared__ float ps[4];
    if ((threadIdx.x & 63) == 0) ps[threadIdx.x >> 6] = s;
    __syncthreads();
    if (threadIdx.x == 0)
        avg[row] = (ps[0] + ps[1] + ps[2] + ps[3]) * (1.0f / LL);
}

// pi = softmax_m( w[m,:] . avg[b,:] ) ; one wave per b
__global__ void pi_k(const float* __restrict__ wgt, const float* __restrict__ avg,
                     float* __restrict__ piOut) {
    const int b = blockIdx.x;
    const int l = threadIdx.x;   // 0..63
    float part[NMIX] = {0.f, 0.f, 0.f, 0.f};
    for (int d = l; d < DK; d += 64) {
        float a = avg[b * DK + d];
        #pragma unroll
        for (int m = 0; m < NMIX; ++m) part[m] += wgt[m * DK + d] * a;
    }
    #pragma unroll
    for (int off = 1; off < 64; off <<= 1) {
        #pragma unroll
        for (int m = 0; m < NMIX; ++m) part[m] += __shfl_xor(part[m], off);
    }
    float mx = fmaxf(fmaxf(part[0], part[1]), fmaxf(part[2], part[3]));
    float e0 = __expf(part[0] - mx), e1 = __expf(part[1] - mx);
    float e2 = __expf(part[2] - mx), e3 = __expf(part[3] - mx);
    float z = e0 + e1 + e2 + e3;
    float mine = (l == 0) ? e0 : (l == 1) ? e1 : (l == 2) ? e2 : e3;
    if (l < NMIX) piOut[b * NMIX + l] = mine / z;
}

// ---------------------------------------------------------------------------
// Q A-fragment hoist from raw f32 query: A[row=q=lc][ch=lg*8+i]; qf[qt][m][c].
__device__ __forceinline__ void hoist_q2(const float* __restrict__ query,
                                         int b, int qrow0, int lg, int lc,
                                         bf16x8 qf[2][4][2]) {
    #pragma unroll
    for (int qt = 0; qt < 2; ++qt)
        #pragma unroll
        for (int m = 0; m < 4; ++m)
            #pragma unroll
            for (int c = 0; c < 2; ++c) {
                const float* src = query + ((size_t)b * DK + m * 64 + c * 32 + lg * 8) * LL
                                   + qrow0 + qt * 16 + lc;
                bf16x8 f;
                #pragma unroll
                for (int i = 0; i < 8; ++i) f[i] = (short)f2bf(src[(size_t)i * LL]);
                qf[qt][m][c] = f;
            }
}

// ---------------------------------------------------------------------------
// Z pre-pass (unchanged, known-good):
// Zh[kh][b][q][m] = sum_{k in half} exp2(S*ES)
__launch_bounds__(256, 4)
__global__ void zsum_k(const float* __restrict__ query,
                       const unsigned short* __restrict__ Kp,
                       float* __restrict__ Zh) {
    const int bid = blockIdx.x;
    const int b    = bid & 7;             // XCD affinity
    const int qt64 = (bid >> 3) & 63;
    const int kh   = bid >> 9;
    const int qb   = qt64 * 32;
    const int tid  = threadIdx.x;
    const int w = tid >> 6, lane = tid & 63, lg = lane >> 4, lc = lane & 15;

    bf16x8 qf[2][4][2];
    hoist_q2(query, b, qb, lg, lc, qf);

    const unsigned short* kpB = Kp + (size_t)b * 128 * 8 * 512;
    const float ES = 0.09016844005555896f;   // log2(e)/16

    float zs[2][4][4];
    #pragma unroll
    for (int qt = 0; qt < 2; ++qt)
        #pragma unroll
        for (int m = 0; m < 4; ++m)
            #pragma unroll
            for (int r = 0; r < 4; ++r) zs[qt][m][r] = 0.f;

    for (int t = 0; t < 16; ++t) {
        const int ktile = kh * 64 + w * 16 + t;
        const unsigned short* kp = kpB + (size_t)ktile * 8 * 512 + lane * 8;
        #pragma unroll
        for (int m = 0; m < 4; ++m) {
            bf16x8 k0 = *reinterpret_cast<const bf16x8*>(kp + (m * 2 + 0) * 512);
            bf16x8 k1 = *reinterpret_cast<const bf16x8*>(kp + (m * 2 + 1) * 512);
            #pragma unroll
            for (int qt = 0; qt < 2; ++qt) {
                f32x4 s = {0.f, 0.f, 0.f, 0.f};
                s = __builtin_amdgcn_mfma_f32_16x16x32_bf16(qf[qt][m][0], k0, s, 0, 0, 0);
                s = __builtin_amdgcn_mfma_f32_16x16x32_bf16(qf[qt][m][1], k1, s, 0, 0, 0);
                #pragma unroll
                for (int r = 0; r < 4; ++r)
                    zs[qt][m][r] += __builtin_amdgcn_exp2f(s[r] * ES);
            }
        }
    }
    #pragma unroll
    for (int qt = 0; qt < 2; ++qt)
        #pragma unroll
        for (int m = 0; m < 4; ++m)
            #pragma unroll
            for (int r = 0; r < 4; ++r) {
                float v = zs[qt][m][r];
                v += __shfl_xor(v, 1);
                v += __shfl_xor(v, 2);
                v += __shfl_xor(v, 4);
                v += __shfl_xor(v, 8);
                zs[qt][m][r] = v;
            }
    __shared__ float Zp[4][2][4][4][4];   // [w][qt][lg][m][r]
    if (lc == 0) {
        #pragma unroll
        for (int qt = 0; qt < 2; ++qt)
            #pragma unroll
            for (int m = 0; m < 4; ++m)
                #pragma unroll
                for (int r = 0; r < 4; ++r) Zp[w][qt][lg][m][r] = zs[qt][m][r];
    }
    __syncthreads();
    if (tid < 128) {
        const int q = tid >> 2, m = tid & 3;
        const int qt = q >> 4, g = (q >> 2) & 3, r = q & 3;
        float z = Zp[0][qt][g][m][r] + Zp[1][qt][g][m][r]
                + Zp[2][qt][g][m][r] + Zp[3][qt][g][m][r];
        Zh[(((size_t)kh * NB + b) * LL + qb + q) * NMIX + m] = z;
    }
}

// ---------------------------------------------------------------------------
// Main kernel v13: fused QK+softmax+attn+PV with K-SPLIT blocks.
// grid 512 = b(8, bid&7) x qt(32) x kh(2). 512 thr / 8 waves; 2 blocks/CU
// (LDS exactly 80KB). Block covers 64 q-rows x 1024 k (its half).
// Per 64k window (16 total, ONE barrier each):
//   stage K(j+1) via gl16 (dbuf) -> QK (wq4 x wk2: 16q x 32k/wave) -> E dbuf
//   (XOR swizzle col ^= (r<<3)^(lg<<4)) -> BAR -> attn nt_store -> PV
//   (wave owns vj={2w,2w+1}; V frags DIRECT from global, read exactly once).
// kh=0 writes out; kh=1 writes Opart; oadd_k combines.
__launch_bounds__(512, 4)
__global__ void mos_attn(const float* __restrict__ query,
                         const unsigned short* __restrict__ Kp,
                         const unsigned short* __restrict__ Vp,
                         const float* __restrict__ Zh,
                         const float* __restrict__ piAll,
                         float* __restrict__ out,
                         float* __restrict__ opart,
                         float* __restrict__ attn) {
    const int bid = blockIdx.x;
    const int b   = bid & 7;             // XCD affinity
    const int qt  = (bid >> 3) & 31;     // 0..31
    const int kh  = bid >> 8;            // 0..1
    const int qb  = qt * 64;
    const int tid = threadIdx.x;
    const int w = tid >> 6, lane = tid & 63, lg = lane >> 4, lc = lane & 15;
    const int wq = w >> 1, wk = w & 1;

    __shared__ __align__(16) unsigned short Ks[2][16384];  // 2 x 32KB (32 frags)
    __shared__ __align__(16) unsigned short E[2][4096];    // 2 x 8KB, pitch 64

    // Q A-fragments for this wave's 16 q-rows: A[row=q=lc][ch]
    bf16x8 qf[4][2];
    #pragma unroll
    for (int m = 0; m < 4; ++m)
        #pragma unroll
        for (int c = 0; c < 2; ++c) {
            const float* src = query + ((size_t)b * DK + m * 64 + c * 32 + lg * 8) * LL
                               + qb + wq * 16 + lc;
            bf16x8 f;
            #pragma unroll
            for (int i = 0; i < 8; ++i) f[i] = (short)f2bf(src[(size_t)i * LL]);
            qf[m][c] = f;
        }

    // C[m][r] = log2(pi_m / Z) for q = qb + wq*16 + lg*4 + r  (FULL-k Z)
    float C[4][4];
    #pragma unroll
    for (int r = 0; r < 4; ++r) {
        const int q = qb + wq * 16 + lg * 4 + r;
        #pragma unroll
        for (int m = 0; m < 4; ++m) {
            float z = Zh[((size_t)b * LL + q) * NMIX + m]
                    + Zh[((size_t)(NB + b) * LL + q) * NMIX + m];
            C[m][r] = __log2f(piAll[b * NMIX + m] / z);
        }
    }

    const unsigned short* kpB = Kp + (size_t)b * 128 * 8 * 512;   // batch base
    const unsigned short* vpB = Vp + (size_t)b * 64 * 16 * 512;
    const float ES = 0.09016844005555896f;    // log2(e)/16

    f32x4 oacc[4][2];   // [qg][vv]
    #pragma unroll
    for (int qg = 0; qg < 4; ++qg)
        #pragma unroll
        for (int vv = 0; vv < 2; ++vv) oacc[qg][vv] = (f32x4){0.f, 0.f, 0.f, 0.f};

    // prologue: stage window 0 of this k-half into Ks[0] (32 frags, 4/wave)
    {
        const size_t f0 = (size_t)(kh * 64) * 8 * 512;   // ktile base kh*64
        #pragma unroll
        for (int s = 0; s < 4; ++s)
            gl16(kpB + f0 + (size_t)(w * 4 + s) * 512 + lane * 8,
                 &Ks[0][(w * 4 + s) * 512]);
    }
    __syncthreads();

    for (int j = 0; j < 16; ++j) {
        const int buf = j & 1;
        // stage next window (drained at this window's barrier)
        if (j < 15) {
            const size_t fn = ((size_t)(kh * 64 + (j + 1) * 4)) * 8 * 512;
            #pragma unroll
            for (int s = 0; s < 4; ++s)
                gl16(kpB + fn + (size_t)(w * 4 + s) * 512 + lane * 8,
                     &Ks[buf ^ 1][(w * 4 + s) * 512]);
        }

        // ---- QK: wave (wq,wk) -> 16q x 32k (2 ktiles) from LDS K frags ----
        #pragma unroll
        for (int t = 0; t < 2; ++t) {
            const int ktile = wk * 2 + t;   // 0..3 within window
            const unsigned short* kf = &Ks[buf][(ktile * 8) * 512 + lane * 8];
            float av[4] = {0.f, 0.f, 0.f, 0.f};
            #pragma unroll
            for (int m = 0; m < 4; ++m) {
                bf16x8 k0 = *reinterpret_cast<const bf16x8*>(kf + (m * 2 + 0) * 512);
                bf16x8 k1 = *reinterpret_cast<const bf16x8*>(kf + (m * 2 + 1) * 512);
                f32x4 s = {0.f, 0.f, 0.f, 0.f};
                s = __builtin_amdgcn_mfma_f32_16x16x32_bf16(qf[m][0], k0, s, 0, 0, 0);
                s = __builtin_amdgcn_mfma_f32_16x16x32_bf16(qf[m][1], k1, s, 0, 0, 0);
                #pragma unroll
                for (int r = 0; r < 4; ++r)
                    av[r] += __builtin_amdgcn_exp2f(fmaf(s[r], ES, C[m][r]));
            }
            // E write: row = wq*16+lg*4+r; col = (ktile*16+lc) ^ (r<<3) ^ (lg<<4)
            #pragma unroll
            for (int r = 0; r < 4; ++r) {
                const int row = wq * 16 + lg * 4 + r;
                const int col = (ktile * 16 + lc) ^ (r << 3) ^ (lg << 4);
                E[buf][row * 64 + col] = f2bf(av[r]);
            }
        }
        __syncthreads();   // single barrier: E ready; gl16(j+1) drained

        // ---- attn store: 64q x 64k, nontemporal f32x4 (2 row-passes) ----
        #pragma unroll
        for (int p = 0; p < 2; ++p) {
            const int row = (tid >> 4) + p * 32;
            const int c4  = (tid & 15) * 4;
            const int ec  = c4 ^ ((row & 3) << 3) ^ (((row >> 2) & 3) << 4);
            bf16x4 e = *reinterpret_cast<const bf16x4*>(&E[buf][row * 64 + ec]);
            f32x4 f;
            #pragma unroll
            for (int i = 0; i < 4; ++i) f[i] = bf2f((unsigned short)e[i]);
            nt_store4(attn + ((size_t)b * LL + qb + row) * LL
                      + kh * 1024 + j * 64 + c4, f);
        }

        // ---- PV: wave owns vj = {2w,2w+1}; V frags direct from global ----
        #pragma unroll
        for (int kc = 0; kc < 2; ++kc) {
            const unsigned short* vpt =
                vpB + ((size_t)(kh * 32 + j * 2 + kc) * 16 + 2 * w) * 512 + lane * 8;
            bf16x8 vf0 = *reinterpret_cast<const bf16x8*>(vpt);
            bf16x8 vf1 = *reinterpret_cast<const bf16x8*>(vpt + 512);
            #pragma unroll
            for (int qg = 0; qg < 4; ++qg) {
                const int row = qg * 16 + lc;
                const int col = (kc * 32 + lg * 8) ^ ((row & 3) << 3)
                                ^ (((row >> 2) & 3) << 4);
                bf16x8 ea = *reinterpret_cast<const bf16x8*>(&E[buf][row * 64 + col]);
                oacc[qg][0] = __builtin_amdgcn_mfma_f32_16x16x32_bf16(ea, vf0, oacc[qg][0], 0, 0, 0);
                oacc[qg][1] = __builtin_amdgcn_mfma_f32_16x16x32_bf16(ea, vf1, oacc[qg][1], 0, 0, 0);
            }
        }
        // no second barrier: next window writes E[buf^1] / stages Ks[buf];
        // all reads of E[buf]/Ks[buf] complete before each wave's next BAR.
    }

    // partial O: kh=0 -> out, kh=1 -> opart
    float* dst = kh ? opart : out;
    #pragma unroll
    for (int qg = 0; qg < 4; ++qg)
        #pragma unroll
        for (int vv = 0; vv < 2; ++vv)
            #pragma unroll
            for (int r = 0; r < 4; ++r)
                dst[((size_t)b * LL + qb + qg * 16 + lg * 4 + r) * DV
                    + (2 * w + vv) * 16 + lc] = oacc[qg][vv][r];
}

// out += opart (combine the two k-half partials)
__global__ void oadd_k(float* __restrict__ out, const float* __restrict__ opart) {
    const size_t i = ((size_t)blockIdx.x * 256 + threadIdx.x) * 4;
    f32x4 a = *reinterpret_cast<const f32x4*>(out + i);
    f32x4 p = *reinterpret_cast<const f32x4*>(opart + i);
    #pragma unroll
    for (int k = 0; k < 4; ++k) a[k] += p[k];
    *reinterpret_cast<f32x4*>(out + i) = a;
}

// ---------------------------------------------------------------------------
extern "C" void kernel_launch(void* const* d_in, const int* in_sizes, int n_in,
                              void* d_out, int out_size, void* d_ws, size_t ws_size,
                              hipStream_t stream) {
    const float* query   = (const float*)d_in[0];   // (8, 256, 2048)
    const float* key     = (const float*)d_in[1];   // (8, 256, 2048)
    const float* value   = (const float*)d_in[2];   // (8, 256, 2048)
    const float* weights = (const float*)d_in[3];   // (4, 256)

    float* out  = (float*)d_out;                    // (8, 2048, 256)
    float* attn = out + (size_t)NB * LL * DV;       // (8, 2048, 2048)

    // workspace (~34.1 MB)
    char* ws = (char*)d_ws;
    float* avg = (float*)ws;                              // 8KB
    float* pi  = (float*)(ws + 8192);                     // 32B
    float* Zh  = (float*)(ws + 12288);                    // 512KB
    unsigned short* Kp = (unsigned short*)(ws + 536576);  // 8.4MB packed K frags
    unsigned short* Vp = Kp + (size_t)NB * LL * DK;       // 8.4MB packed V frags
    float* Opart = (float*)(ws + 536576 + 2 * (size_t)NB * LL * DK * 2);  // 16.8MB

    avg_k<<<NB * DK, 256, 0, stream>>>(query, avg);
    pi_k<<<NB, 64, 0, stream>>>(weights, avg, pi);
    pack_kv<<<4096, 256, 0, stream>>>(key, value, Kp, Vp);
    zsum_k<<<1024, 256, 0, stream>>>(query, Kp, Zh);
    mos_attn<<<512, 512, 0, stream>>>(query, Kp, Vp, Zh, pi, out, Opart, attn);
    oadd_k<<<(NB * LL * DV) / 1024, 256, 0, stream>>>(out, Opart);
}